// Round 11
// baseline (320.143 us; speedup 1.0000x reference)
//
#include <hip/hip_runtime.h>

#define NFEAT 512
#define NCLS  40
#define NPAD  48          // NCLS padded to 3 MFMA n-tiles of 16
#define DM 128            // padded bucket width (legacy direct path)

// partition path parameters
#define NCB        256    // nodes per coarse bucket (c >> 8)
#define SLICE_CAP  40     // per (block,bucket) slice capacity (mean 8)
#define P1B        1024   // phase-1 block count
#define SPT        (P1B / 256)   // slices per thread in phase 2
#define BCAP       16384  // fixed src region per bucket (mean 8192)
#define OVF_CAP    65536  // overflow ring capacity (virtually never used)

typedef __attribute__((ext_vector_type(8))) short bf16x8;   // 8 bf16 (4 VGPRs)
typedef __attribute__((ext_vector_type(4))) float f32x4;

__device__ __forceinline__ unsigned short f2bf(float f) {   // RNE f32->bf16
    unsigned int u = __builtin_bit_cast(unsigned int, f);
    return (unsigned short)((u + 0x7FFFu + ((u >> 16) & 1u)) >> 16);
}
__device__ __forceinline__ float bf2f(unsigned short h) {
    return __builtin_bit_cast(float, (unsigned int)h << 16);
}

__device__ __forceinline__ void load_edge(const void* adj, int int32_mode,
                                          int e, int E, int& r, int& c) {
    if (int32_mode) {
        const int* a = (const int*)adj;
        r = a[e]; c = a[(size_t)E + e];
    } else {
        const long long* a = (const long long*)adj;
        r = (int)a[e]; c = (int)a[(size_t)E + e];
    }
}

// ---------------------------------------------------------------------------
// W [40][512] f32 -> Wb [48][512] bf16 (rows 40..47 zero) + zero scalars.
// ---------------------------------------------------------------------------
__global__ void wconv_kernel(const float* __restrict__ W,
                             unsigned short* __restrict__ Wb,
                             unsigned int* __restrict__ flag,
                             int* __restrict__ ovf_cnt) {
    int i = blockIdx.x * blockDim.x + threadIdx.x;
    if (i == 0) { *flag = 0u; *ovf_cnt = 0; }
    if (i >= NPAD * NFEAT) return;
    int n = i >> 9;
    float v = (n < NCLS) ? W[i] : 0.0f;
    Wb[i] = f2bf(v);
}

// ---------------------------------------------------------------------------
// x [N][512] f32 -> xb bf16. Pure streaming, float4 in / ushort4 out.
// ---------------------------------------------------------------------------
__global__ void xconv_kernel(const float* __restrict__ x,
                             unsigned short* __restrict__ xb, int total4) {
    int stride = gridDim.x * blockDim.x;
    for (int i = blockIdx.x * blockDim.x + threadIdx.x; i < total4; i += stride) {
        float4 v = reinterpret_cast<const float4*>(x)[i];
        ushort4 h;
        h.x = f2bf(v.x); h.y = f2bf(v.y); h.z = f2bf(v.z); h.w = f2bf(v.w);
        reinterpret_cast<ushort4*>(xb)[i] = h;
    }
}

// ---------------------------------------------------------------------------
// GEMM from bf16 xb: one wave per 16-row m-tile, direct A loads (16B/lane,
// 4 ks-lanes cover one full 64B line per row), no LDS, no barriers.
// ---------------------------------------------------------------------------
__global__ __launch_bounds__(256) void gemm_kernel(
        const unsigned short* __restrict__ xb,
        const unsigned short* __restrict__ Wb,
        unsigned short* __restrict__ xwb, int N) {
    const int wid  = (blockIdx.x * blockDim.x + threadIdx.x) >> 6;
    const int lane = threadIdx.x & 63;
    const int m0 = wid * 16;
    if (m0 >= N) return;
    const int frow = lane & 15, ks = lane >> 4;
    int grow = m0 + frow; if (grow > N - 1) grow = N - 1;
    const unsigned short* xr  = xb + (size_t)grow * NFEAT + ks * 8;
    const unsigned short* wb0 = Wb + (size_t)frow * NFEAT + ks * 8;
    const unsigned short* wb1 = wb0 + (size_t)16 * NFEAT;
    const unsigned short* wb2 = wb0 + (size_t)32 * NFEAT;

    f32x4 acc0 = {0.f, 0.f, 0.f, 0.f};
    f32x4 acc1 = {0.f, 0.f, 0.f, 0.f};
    f32x4 acc2 = {0.f, 0.f, 0.f, 0.f};

#pragma unroll
    for (int kk = 0; kk < NFEAT; kk += 32) {
        bf16x8 a  = *reinterpret_cast<const bf16x8*>(xr + kk);
        bf16x8 b0 = *reinterpret_cast<const bf16x8*>(wb0 + kk);
        bf16x8 b1 = *reinterpret_cast<const bf16x8*>(wb1 + kk);
        bf16x8 b2 = *reinterpret_cast<const bf16x8*>(wb2 + kk);
        acc0 = __builtin_amdgcn_mfma_f32_16x16x32_bf16(a, b0, acc0, 0, 0, 0);
        acc1 = __builtin_amdgcn_mfma_f32_16x16x32_bf16(a, b1, acc1, 0, 0, 0);
        acc2 = __builtin_amdgcn_mfma_f32_16x16x32_bf16(a, b2, acc2, 0, 0, 0);
    }

    const int ccol = frow;
#pragma unroll
    for (int i = 0; i < 4; ++i) {
        int crow = m0 + ks * 4 + i;
        if (crow < N) {
            unsigned short* orow = xwb + (size_t)crow * NCLS;
            orow[ccol]      = f2bf(acc0[i]);
            orow[16 + ccol] = f2bf(acc1[i]);
            if (ccol < 8) orow[32 + ccol] = f2bf(acc2[i]);
        }
    }
}

// ---------------------------------------------------------------------------
// Phase 1 (standalone): P1B blocks, private slices, LDS cursors (1.6 KB).
// ---------------------------------------------------------------------------
__global__ void phase1_kernel(const void* __restrict__ adj,
                              unsigned int* __restrict__ slices,
                              int* __restrict__ slice_cnt,
                              unsigned long long* __restrict__ ovf,
                              int* __restrict__ ovf_cnt,
                              int E, int N, int NB) {
    __shared__ int lcur[512];
    __shared__ unsigned int det;
    const int blk = blockIdx.x;
    for (int i = threadIdx.x; i < NB; i += 256) lcur[i] = 0;
    if (threadIdx.x == 0) det = 0u;
    __syncthreads();
    // inline dtype detect: odd 32-bit words all-zero <=> int64 storage
    const unsigned int* aw = (const unsigned int*)adj;
    unsigned int v = aw[2 * threadIdx.x + 1] | aw[2 * (threadIdx.x + 256) + 1];
    if (v) atomicOr(&det, 1u);
    __syncthreads();
    const int m32 = (det != 0);
    const int chunk = (E + P1B - 1) / P1B;
    const int e0 = blk * chunk;
    const int e1 = min(E, e0 + chunk);
    for (int e = e0 + (int)threadIdx.x; e < e1; e += 256) {
        int r, c;
        load_edge(adj, m32, e, E, r, c);
        if (r == c) continue;
        if ((unsigned)r >= (unsigned)N || (unsigned)c >= (unsigned)N) continue;
        int b = c >> 8;
        unsigned int p = ((unsigned int)(c & 255) << 17) | (unsigned int)r;
        int pos = atomicAdd(&lcur[b], 1);            // LDS atomic
        if (pos < SLICE_CAP) {
            slices[((size_t)b * P1B + blk) * SLICE_CAP + pos] = p;
        } else {
            int oi = atomicAdd(ovf_cnt, 1);
            if (oi < OVF_CAP)
                ovf[oi] = ((unsigned long long)b << 32) | p;
        }
    }
    __syncthreads();
    for (int i = threadIdx.x; i < NB; i += 256)
        slice_cnt[(size_t)i * P1B + blk] = min(lcur[i], SLICE_CAP);
}

// ---------------------------------------------------------------------------
// Phase 2: one block per bucket; thread t owns slices [t*SPT, t*SPT+SPT).
// LDS histogram -> scan -> compact CSR placement at fixed bs = b*BCAP.
// ---------------------------------------------------------------------------
__global__ void phase2_kernel(const unsigned int* __restrict__ slices,
                              const int* __restrict__ slice_cnt,
                              const unsigned long long* __restrict__ ovf,
                              const int* __restrict__ ovf_cnt,
                              int* __restrict__ starts,
                              int* __restrict__ cnt,
                              int* __restrict__ src, int N) {
    __shared__ int hist[NCB];
    __shared__ int lscan[NCB];
    __shared__ int cur[NCB];
    const int b = blockIdx.x;
    const int t = threadIdx.x;            // 256 threads
    hist[t] = 0;
    __syncthreads();

    int myk[SPT];
    const unsigned int* mysl[SPT];
#pragma unroll
    for (int s = 0; s < SPT; ++s) {
        int sl = t * SPT + s;
        myk[s]  = slice_cnt[(size_t)b * P1B + sl];
        mysl[s] = slices + ((size_t)b * P1B + sl) * SLICE_CAP;
        for (int i = 0; i < myk[s]; ++i)
            atomicAdd(&hist[mysl[s][i] >> 17], 1);
    }
    const int no = min(*ovf_cnt, OVF_CAP);
    for (int i = t; i < no; i += 256)
        if ((int)(ovf[i] >> 32) == b)
            atomicAdd(&hist[((unsigned int)ovf[i]) >> 17], 1);
    __syncthreads();

    int h = hist[t];
    lscan[t] = h;
    __syncthreads();
    for (int o = 1; o < 256; o <<= 1) {
        int v = (t >= o) ? lscan[t - o] : 0;
        __syncthreads();
        lscan[t] += v;
        __syncthreads();
    }
    int excl = lscan[t] - h;
    cur[t] = excl;
    const int bs = b * BCAP;
    const int c0 = b * NCB;
    if (c0 + t < N) {
        starts[c0 + t] = bs + excl;
        cnt[c0 + t] = h;
    }
    __syncthreads();

#pragma unroll
    for (int s = 0; s < SPT; ++s) {
        for (int i = 0; i < myk[s]; ++i) {
            unsigned int p = mysl[s][i];
            int pos = atomicAdd(&cur[p >> 17], 1);   // LDS atomic
            if (pos < BCAP) src[bs + pos] = (int)(p & 0x1FFFFu);
        }
    }
    for (int i = t; i < no; i += 256) {
        if ((int)(ovf[i] >> 32) == b) {
            unsigned int p = (unsigned int)ovf[i];
            int pos = atomicAdd(&cur[p >> 17], 1);
            if (pos < BCAP) src[bs + pos] = (int)(p & 0x1FFFFu);
        }
    }
}

// ===========================================================================
// LEGACY DIRECT PATH (fallback only)
// ===========================================================================
__global__ void detect_kernel(const unsigned int* __restrict__ w,
                              unsigned int* __restrict__ flag) {
    unsigned int v = 0;
    for (int i = 1 + 2 * (int)threadIdx.x; i < 65536; i += 2 * (int)blockDim.x)
        v |= w[i];
    if (v) atomicOr(flag, 1u);
}

__global__ void fused_bucket_kernel(const void* __restrict__ adj,
                                    const unsigned int* __restrict__ flag,
                                    int* __restrict__ cnt,
                                    int* __restrict__ src2, int E, int N) {
    int e = blockIdx.x * blockDim.x + threadIdx.x;
    if (e >= E) return;
    int r, c;
    load_edge(adj, *flag, e, E, r, c);
    if (r == c) return;
    if ((unsigned)r >= (unsigned)N || (unsigned)c >= (unsigned)N) return;
    int pos = atomicAdd(&cnt[c], 1);
    if (pos < DM) src2[(size_t)c * DM + pos] = r;
}

// ---------------------------------------------------------------------------
// Gather: one wave per node. lane = (edge-group g 0..5, class-quad cl 0..9).
// ---------------------------------------------------------------------------
__global__ void gather_kernel(const unsigned short* __restrict__ xwb,
                              const int* __restrict__ starts,
                              const int* __restrict__ deg,
                              const int* __restrict__ src,
                              const float* __restrict__ bias,
                              float* __restrict__ out, int N, int dm) {
    int wid = (blockIdx.x * blockDim.x + threadIdx.x) >> 6;
    int lane = threadIdx.x & 63;
    if (wid >= N) return;
    int start, d;
    if (dm > 0) {
        start = wid * dm;
        d = min(deg[wid], dm);
    } else {
        start = starts[wid];
        d = deg[wid];
    }
    start = __builtin_amdgcn_readfirstlane(start);
    d     = __builtin_amdgcn_readfirstlane(d);

    const int g  = lane / 10;        // 0..5 edge groups; lanes 60-63 idle
    const int cl = lane % 10;        // class quad
    const bool lact = (g < 6);
    float a0 = 0.f, a1 = 0.f, a2 = 0.f, a3 = 0.f;

    if (g == 0) {                    // self-loop row
        ushort4 v = *reinterpret_cast<const ushort4*>(
            xwb + (size_t)wid * NCLS + cl * 4);
        a0 = bf2f(v.x); a1 = bf2f(v.y); a2 = bf2f(v.z); a3 = bf2f(v.w);
    }

    const int* sp = src + start;
    for (int e = 0; e < d; e += 12) {
        int i0 = e + g, i1 = e + 6 + g;
        if (lact && i0 < d) {
            int r = sp[i0];
            ushort4 v = *reinterpret_cast<const ushort4*>(
                xwb + (size_t)r * NCLS + cl * 4);
            a0 += bf2f(v.x); a1 += bf2f(v.y); a2 += bf2f(v.z); a3 += bf2f(v.w);
        }
        if (lact && i1 < d) {
            int r = sp[i1];
            ushort4 v = *reinterpret_cast<const ushort4*>(
                xwb + (size_t)r * NCLS + cl * 4);
            a0 += bf2f(v.x); a1 += bf2f(v.y); a2 += bf2f(v.z); a3 += bf2f(v.w);
        }
    }

    a0 += __shfl_down(a0, 30); a1 += __shfl_down(a1, 30);
    a2 += __shfl_down(a2, 30); a3 += __shfl_down(a3, 30);
    {
        float u0 = __shfl_down(a0, 10), v0 = __shfl_down(a0, 20);
        float u1 = __shfl_down(a1, 10), v1 = __shfl_down(a1, 20);
        float u2 = __shfl_down(a2, 10), v2 = __shfl_down(a2, 20);
        float u3 = __shfl_down(a3, 10), v3 = __shfl_down(a3, 20);
        a0 += u0 + v0; a1 += u1 + v1; a2 += u2 + v2; a3 += u3 + v3;
    }

    if (lane < 10) {
        float scale = 1.0f / (float)(d + 1);
        float4 bb = *reinterpret_cast<const float4*>(bias + cl * 4);
        float4 o;
        o.x = fmaf(scale, a0, bb.x);
        o.y = fmaf(scale, a1, bb.y);
        o.z = fmaf(scale, a2, bb.z);
        o.w = fmaf(scale, a3, bb.w);
        *reinterpret_cast<float4*>(out + (size_t)wid * NCLS + cl * 4) = o;
    }
}

extern "C" void kernel_launch(void* const* d_in, const int* in_sizes, int n_in,
                              void* d_out, int out_size, void* d_ws, size_t ws_size,
                              hipStream_t stream) {
    const float* x   = (const float*)d_in[0];
    const void*  adj = d_in[1];
    const float* W   = (const float*)d_in[2];
    const float* b   = (const float*)d_in[3];
    float* out = (float*)d_out;

    const int N = in_sizes[0] / NFEAT;   // 100000
    const int E = in_sizes[1] / 2;       // 3200000
    const int NB = (N + NCB - 1) / NCB;  // 391 coarse buckets
    const int GEMMB = (N + 63) / 64;     // 4 m-tiles of 16 rows per block

    char* ws = (char*)d_ws;
    size_t off = 0;
    auto alloc = [&](size_t bytes) { char* p = ws + off; off += (bytes + 15) & ~size_t(15); return p; };

    unsigned short* xwb = (unsigned short*)alloc((size_t)N * NCLS * 2);   // 8 MB
    int*   cnt          = (int*)  alloc((size_t)N * sizeof(int));
    unsigned int* flag  = (unsigned int*)alloc(16);
    int*   ovf_cnt      = (int*)  alloc(16);
    unsigned short* Wb  = (unsigned short*)alloc((size_t)NPAD * NFEAT * 2);
    unsigned short* xb  = (unsigned short*)alloc((size_t)N * NFEAT * 2);  // 102 MB

    const size_t part_need = off
        + (((size_t)NB * P1B * SLICE_CAP * 4 + 15) & ~size_t(15))   // slices 64 MB
        + (((size_t)NB * P1B * 4 + 15) & ~size_t(15))               // slice_cnt 1.6 MB
        + (((size_t)N * 4 + 15) & ~size_t(15))                      // starts
        + (((size_t)NB * BCAP * 4 + 15) & ~size_t(15))              // src 25.6 MB
        + (size_t)OVF_CAP * 8;                                      // ovf ring
    const bool partition = (N <= NCB * 512) && (NB <= 512) && (E >= 512)
                           && (part_need <= ws_size);
    const size_t direct_need = off + (size_t)N * DM * sizeof(int);
    const bool direct = !partition && (direct_need <= ws_size);

    wconv_kernel<<<(NPAD * NFEAT + 255) / 256, 256, 0, stream>>>(W, Wb, flag, ovf_cnt);
    xconv_kernel<<<2048, 256, 0, stream>>>(x, xb, N * (NFEAT / 4));

    if (partition) {
        unsigned int* slices = (unsigned int*)alloc((size_t)NB * P1B * SLICE_CAP * 4);
        int* slice_cnt = (int*)alloc((size_t)NB * P1B * 4);
        int* starts = (int*)alloc((size_t)N * 4);
        int* src    = (int*)alloc((size_t)NB * BCAP * 4);
        unsigned long long* ovf = (unsigned long long*)alloc((size_t)OVF_CAP * 8);

        phase1_kernel<<<P1B, 256, 0, stream>>>(adj, slices, slice_cnt,
                                               ovf, ovf_cnt, E, N, NB);
        gemm_kernel<<<GEMMB, 256, 0, stream>>>(xb, Wb, xwb, N);
        phase2_kernel<<<NB, 256, 0, stream>>>(slices, slice_cnt, ovf, ovf_cnt,
                                              starts, cnt, src, N);
        gather_kernel<<<(N * 64 + 255) / 256, 256, 0, stream>>>(
            xwb, starts, cnt, src, b, out, N, 0);
    } else if (direct) {
        int* src2 = (int*)alloc((size_t)N * DM * sizeof(int));
        hipMemsetAsync(cnt, 0, (size_t)N * sizeof(int), stream);
        detect_kernel<<<1, 512, 0, stream>>>((const unsigned int*)adj, flag);
        gemm_kernel<<<GEMMB, 256, 0, stream>>>(xb, Wb, xwb, N);
        fused_bucket_kernel<<<(E + 255) / 256, 256, 0, stream>>>(adj, flag, cnt, src2, E, N);
        gather_kernel<<<(N * 64 + 255) / 256, 256, 0, stream>>>(
            xwb, nullptr, cnt, src2, b, out, N, DM);
    }
}

// Round 12
// 246.066 us; speedup vs baseline: 1.3010x; 1.3010x over previous
//
#include <hip/hip_runtime.h>

#define NFEAT 512
#define NCLS  40
#define NPAD  48          // NCLS padded to 3 MFMA n-tiles of 16
#define DM 128            // padded bucket width (legacy direct path)

// partition path parameters
#define NCB     256       // nodes per coarse bucket (c >> 8)
#define P1B     512       // phase-1 block count
#define CH      2048      // edges per LDS sort chunk
#define SCAP    64        // slice capacity per (bucket, block); mean 16
#define SPT     (P1B / 256)   // slices per thread in phase 2
#define BCAP    16384     // fixed src region per bucket (mean 8192)
#define OVF_CAP 65536     // overflow ring capacity (virtually never used)

typedef __attribute__((ext_vector_type(8))) short bf16x8;   // 8 bf16 (4 VGPRs)
typedef __attribute__((ext_vector_type(4))) float f32x4;

__device__ __forceinline__ unsigned short f2bf(float f) {   // RNE f32->bf16
    unsigned int u = __builtin_bit_cast(unsigned int, f);
    return (unsigned short)((u + 0x7FFFu + ((u >> 16) & 1u)) >> 16);
}
__device__ __forceinline__ float bf2f(unsigned short h) {
    return __builtin_bit_cast(float, (unsigned int)h << 16);
}

__device__ __forceinline__ void load_edge(const void* adj, int int32_mode,
                                          int e, int E, int& r, int& c) {
    if (int32_mode) {
        const int* a = (const int*)adj;
        r = a[e]; c = a[(size_t)E + e];
    } else {
        const long long* a = (const long long*)adj;
        r = (int)a[e]; c = (int)a[(size_t)E + e];
    }
}

// ---------------------------------------------------------------------------
// W [40][512] f32 -> Wb [48][512] bf16 (rows 40..47 zero) + zero scalars.
// ---------------------------------------------------------------------------
__global__ void wconv_kernel(const float* __restrict__ W,
                             unsigned short* __restrict__ Wb,
                             unsigned int* __restrict__ flag,
                             int* __restrict__ ovf_cnt) {
    int i = blockIdx.x * blockDim.x + threadIdx.x;
    if (i == 0) { *flag = 0u; *ovf_cnt = 0; }
    if (i >= NPAD * NFEAT) return;
    int n = i >> 9;
    float v = (n < NCLS) ? W[i] : 0.0f;
    Wb[i] = f2bf(v);
}

// ---------------------------------------------------------------------------
// GEMM: f32 x loads (128B contiguous per 4 ks-lanes per row), in-register
// bf16 convert, MFMA, bf16 output. One wave per 16-row m-tile.
// ---------------------------------------------------------------------------
__global__ __launch_bounds__(256) void gemm_kernel(
        const float* __restrict__ x, const unsigned short* __restrict__ Wb,
        unsigned short* __restrict__ xwb, int N) {
    const int wid  = (blockIdx.x * blockDim.x + threadIdx.x) >> 6;
    const int lane = threadIdx.x & 63;
    const int m0 = wid * 16;
    if (m0 >= N) return;
    const int frow = lane & 15, ks = lane >> 4;
    int grow = m0 + frow; if (grow > N - 1) grow = N - 1;
    const float* xr = x + (size_t)grow * NFEAT + ks * 8;
    const unsigned short* wb0 = Wb + (size_t)frow * NFEAT + ks * 8;
    const unsigned short* wb1 = wb0 + (size_t)16 * NFEAT;
    const unsigned short* wb2 = wb0 + (size_t)32 * NFEAT;

    f32x4 acc0 = {0.f, 0.f, 0.f, 0.f};
    f32x4 acc1 = {0.f, 0.f, 0.f, 0.f};
    f32x4 acc2 = {0.f, 0.f, 0.f, 0.f};

#pragma unroll
    for (int kk = 0; kk < NFEAT; kk += 32) {
        float4 xa = *reinterpret_cast<const float4*>(xr + kk);
        float4 xb = *reinterpret_cast<const float4*>(xr + kk + 4);
        bf16x8 a;
        a[0] = (short)f2bf(xa.x); a[1] = (short)f2bf(xa.y);
        a[2] = (short)f2bf(xa.z); a[3] = (short)f2bf(xa.w);
        a[4] = (short)f2bf(xb.x); a[5] = (short)f2bf(xb.y);
        a[6] = (short)f2bf(xb.z); a[7] = (short)f2bf(xb.w);
        bf16x8 b0 = *reinterpret_cast<const bf16x8*>(wb0 + kk);
        bf16x8 b1 = *reinterpret_cast<const bf16x8*>(wb1 + kk);
        bf16x8 b2 = *reinterpret_cast<const bf16x8*>(wb2 + kk);
        acc0 = __builtin_amdgcn_mfma_f32_16x16x32_bf16(a, b0, acc0, 0, 0, 0);
        acc1 = __builtin_amdgcn_mfma_f32_16x16x32_bf16(a, b1, acc1, 0, 0, 0);
        acc2 = __builtin_amdgcn_mfma_f32_16x16x32_bf16(a, b2, acc2, 0, 0, 0);
    }

    const int ccol = frow;
#pragma unroll
    for (int i = 0; i < 4; ++i) {
        int crow = m0 + ks * 4 + i;
        if (crow < N) {
            unsigned short* orow = xwb + (size_t)crow * NCLS;
            orow[ccol]      = f2bf(acc0[i]);
            orow[16 + ccol] = f2bf(acc1[i]);
            if (ccol < 8) orow[32 + ccol] = f2bf(acc2[i]);
        }
    }
}

// ---------------------------------------------------------------------------
// Phase 1 v2: LDS chunk-sort. Each block sorts 2048-edge chunks by bucket in
// LDS, then writes out segment-ordered (consecutive threads -> consecutive
// addresses within each bucket segment). Kills the 64-lines-per-store scatter
// that capped the old phase1 at ~20G lines/s (~150 us).
// ---------------------------------------------------------------------------
__global__ __launch_bounds__(256) void phase1_kernel(
        const void* __restrict__ adj,
        unsigned int* __restrict__ slices,
        int* __restrict__ slice_cnt,
        unsigned long long* __restrict__ ovf,
        int* __restrict__ ovf_cnt,
        int E, int N, int NB) {
    __shared__ unsigned int   pbuf[CH];     // packed (c&255)<<17 | r
    __shared__ unsigned short bbuf[CH];     // bucket id (0xFFFF invalid)
    __shared__ unsigned int   sbuf[CH];     // sorted packed
    __shared__ unsigned int   obuf[CH];     // sorted global target
    __shared__ int hist[512], base[512], cur[512], gcur[512];
    __shared__ int scn[256];
    __shared__ unsigned int det;

    const int t = threadIdx.x, blk = blockIdx.x;
    for (int i = t; i < 512; i += 256) gcur[i] = 0;
    if (t == 0) det = 0u;
    __syncthreads();
    // inline dtype detect: odd 32-bit words all-zero <=> int64 storage
    const unsigned int* aw = (const unsigned int*)adj;
    unsigned int dv = aw[2 * t + 1] | aw[2 * (t + 256) + 1];
    if (dv) atomicOr(&det, 1u);
    __syncthreads();
    const int m32 = (det != 0);

    const int per_blk = (E + P1B - 1) / P1B;
    const int e0 = blk * per_blk;
    const int e1 = min(E, e0 + per_blk);

    for (int cb = e0; cb < e1; cb += CH) {
        const int n = min(CH, e1 - cb);
        // 1. load + classify (coalesced)
        for (int i = t; i < CH; i += 256) {
            unsigned short b = 0xFFFFu; unsigned int p = 0;
            if (i < n) {
                int r, c;
                load_edge(adj, m32, cb + i, E, r, c);
                if (r != c && (unsigned)r < (unsigned)N && (unsigned)c < (unsigned)N) {
                    b = (unsigned short)(c >> 8);
                    p = ((unsigned int)(c & 255) << 17) | (unsigned int)r;
                }
            }
            bbuf[i] = b; pbuf[i] = p;
        }
        // 2. zero hist
        for (int i = t; i < 512; i += 256) hist[i] = 0;
        __syncthreads();
        // 3. histogram
        for (int i = t; i < CH; i += 256) {
            unsigned short b = bbuf[i];
            if (b != 0xFFFFu) atomicAdd(&hist[b], 1);
        }
        __syncthreads();
        // 4. exclusive scan over 512 (each thread owns 2 entries)
        int h0 = hist[2 * t], h1 = hist[2 * t + 1];
        int s = h0 + h1;
        scn[t] = s;
        __syncthreads();
        for (int o = 1; o < 256; o <<= 1) {
            int v = (t >= o) ? scn[t - o] : 0;
            __syncthreads();
            scn[t] += v;
            __syncthreads();
        }
        int excl = scn[t] - s;
        base[2 * t] = excl;           cur[2 * t] = excl;
        base[2 * t + 1] = excl + h0;  cur[2 * t + 1] = excl + h0;
        __syncthreads();
        // 5. scatter into sorted LDS order + compute global targets
        for (int i = t; i < CH; i += 256) {
            unsigned short b = bbuf[i];
            if (b != 0xFFFFu) {
                unsigned int p = pbuf[i];
                int pos = atomicAdd(&cur[b], 1);
                int rank = gcur[b] + (pos - base[b]);
                unsigned int tgt;
                if (rank < SCAP) {
                    tgt = ((unsigned int)b * P1B + (unsigned int)blk) * SCAP + rank;
                } else {
                    tgt = 0xFFFFFFFFu;
                    int oi = atomicAdd(ovf_cnt, 1);
                    if (oi < OVF_CAP)
                        ovf[oi] = ((unsigned long long)b << 32) | p;
                }
                sbuf[pos] = p;
                obuf[pos] = tgt;
            }
        }
        __syncthreads();
        // 6. coalesced write-out (consecutive i -> consecutive tgt per segment)
        const int nvalid = cur[511];
        for (int i = t; i < nvalid; i += 256) {
            unsigned int tgt = obuf[i];
            if (tgt != 0xFFFFFFFFu) slices[tgt] = sbuf[i];
        }
        // 7. advance persistent per-bucket cursors
        gcur[2 * t]     += h0;
        gcur[2 * t + 1] += h1;
        __syncthreads();   // protects pbuf/bbuf rewrite + hist zero next chunk
    }

    for (int i = t; i < NB; i += 256)
        slice_cnt[(size_t)i * P1B + blk] = min(gcur[i], SCAP);
}

// ---------------------------------------------------------------------------
// Phase 2: one block per bucket; thread t owns slices [t*SPT, +SPT).
// LDS histogram -> scan -> compact CSR placement at fixed bs = b*BCAP.
// ---------------------------------------------------------------------------
__global__ void phase2_kernel(const unsigned int* __restrict__ slices,
                              const int* __restrict__ slice_cnt,
                              const unsigned long long* __restrict__ ovf,
                              const int* __restrict__ ovf_cnt,
                              int* __restrict__ starts,
                              int* __restrict__ cnt,
                              int* __restrict__ src, int N) {
    __shared__ int hist[NCB];
    __shared__ int lscan[NCB];
    __shared__ int cur[NCB];
    const int b = blockIdx.x;
    const int t = threadIdx.x;            // 256 threads
    hist[t] = 0;
    __syncthreads();

    int myk[SPT];
    const unsigned int* mysl[SPT];
#pragma unroll
    for (int s = 0; s < SPT; ++s) {
        int sl = t * SPT + s;
        myk[s]  = slice_cnt[(size_t)b * P1B + sl];
        mysl[s] = slices + ((size_t)b * P1B + sl) * SCAP;
        for (int i = 0; i < myk[s]; ++i)
            atomicAdd(&hist[mysl[s][i] >> 17], 1);
    }
    const int no = min(*ovf_cnt, OVF_CAP);
    for (int i = t; i < no; i += 256)
        if ((int)(ovf[i] >> 32) == b)
            atomicAdd(&hist[((unsigned int)ovf[i]) >> 17], 1);
    __syncthreads();

    int h = hist[t];
    lscan[t] = h;
    __syncthreads();
    for (int o = 1; o < 256; o <<= 1) {
        int v = (t >= o) ? lscan[t - o] : 0;
        __syncthreads();
        lscan[t] += v;
        __syncthreads();
    }
    int excl = lscan[t] - h;
    cur[t] = excl;
    const int bs = b * BCAP;
    const int c0 = b * NCB;
    if (c0 + t < N) {
        starts[c0 + t] = bs + excl;
        cnt[c0 + t] = h;
    }
    __syncthreads();

#pragma unroll
    for (int s = 0; s < SPT; ++s) {
        for (int i = 0; i < myk[s]; ++i) {
            unsigned int p = mysl[s][i];
            int pos = atomicAdd(&cur[p >> 17], 1);   // LDS atomic
            if (pos < BCAP) src[bs + pos] = (int)(p & 0x1FFFFu);
        }
    }
    for (int i = t; i < no; i += 256) {
        if ((int)(ovf[i] >> 32) == b) {
            unsigned int p = (unsigned int)ovf[i];
            int pos = atomicAdd(&cur[p >> 17], 1);
            if (pos < BCAP) src[bs + pos] = (int)(p & 0x1FFFFu);
        }
    }
}

// ===========================================================================
// LEGACY DIRECT PATH (fallback only)
// ===========================================================================
__global__ void detect_kernel(const unsigned int* __restrict__ w,
                              unsigned int* __restrict__ flag) {
    unsigned int v = 0;
    for (int i = 1 + 2 * (int)threadIdx.x; i < 65536; i += 2 * (int)blockDim.x)
        v |= w[i];
    if (v) atomicOr(flag, 1u);
}

__global__ void fused_bucket_kernel(const void* __restrict__ adj,
                                    const unsigned int* __restrict__ flag,
                                    int* __restrict__ cnt,
                                    int* __restrict__ src2, int E, int N) {
    int e = blockIdx.x * blockDim.x + threadIdx.x;
    if (e >= E) return;
    int r, c;
    load_edge(adj, *flag, e, E, r, c);
    if (r == c) return;
    if ((unsigned)r >= (unsigned)N || (unsigned)c >= (unsigned)N) return;
    int pos = atomicAdd(&cnt[c], 1);
    if (pos < DM) src2[(size_t)c * DM + pos] = r;
}

// ---------------------------------------------------------------------------
// Gather: one wave per node. lane = (edge-group g 0..5, class-quad cl 0..9).
// ---------------------------------------------------------------------------
__global__ void gather_kernel(const unsigned short* __restrict__ xwb,
                              const int* __restrict__ starts,
                              const int* __restrict__ deg,
                              const int* __restrict__ src,
                              const float* __restrict__ bias,
                              float* __restrict__ out, int N, int dm) {
    int wid = (blockIdx.x * blockDim.x + threadIdx.x) >> 6;
    int lane = threadIdx.x & 63;
    if (wid >= N) return;
    int start, d;
    if (dm > 0) {
        start = wid * dm;
        d = min(deg[wid], dm);
    } else {
        start = starts[wid];
        d = deg[wid];
    }
    start = __builtin_amdgcn_readfirstlane(start);
    d     = __builtin_amdgcn_readfirstlane(d);

    const int g  = lane / 10;        // 0..5 edge groups; lanes 60-63 idle
    const int cl = lane % 10;        // class quad
    const bool lact = (g < 6);
    float a0 = 0.f, a1 = 0.f, a2 = 0.f, a3 = 0.f;

    if (g == 0) {                    // self-loop row
        ushort4 v = *reinterpret_cast<const ushort4*>(
            xwb + (size_t)wid * NCLS + cl * 4);
        a0 = bf2f(v.x); a1 = bf2f(v.y); a2 = bf2f(v.z); a3 = bf2f(v.w);
    }

    const int* sp = src + start;
    for (int e = 0; e < d; e += 12) {
        int i0 = e + g, i1 = e + 6 + g;
        if (lact && i0 < d) {
            int r = sp[i0];
            ushort4 v = *reinterpret_cast<const ushort4*>(
                xwb + (size_t)r * NCLS + cl * 4);
            a0 += bf2f(v.x); a1 += bf2f(v.y); a2 += bf2f(v.z); a3 += bf2f(v.w);
        }
        if (lact && i1 < d) {
            int r = sp[i1];
            ushort4 v = *reinterpret_cast<const ushort4*>(
                xwb + (size_t)r * NCLS + cl * 4);
            a0 += bf2f(v.x); a1 += bf2f(v.y); a2 += bf2f(v.z); a3 += bf2f(v.w);
        }
    }

    a0 += __shfl_down(a0, 30); a1 += __shfl_down(a1, 30);
    a2 += __shfl_down(a2, 30); a3 += __shfl_down(a3, 30);
    {
        float u0 = __shfl_down(a0, 10), v0 = __shfl_down(a0, 20);
        float u1 = __shfl_down(a1, 10), v1 = __shfl_down(a1, 20);
        float u2 = __shfl_down(a2, 10), v2 = __shfl_down(a2, 20);
        float u3 = __shfl_down(a3, 10), v3 = __shfl_down(a3, 20);
        a0 += u0 + v0; a1 += u1 + v1; a2 += u2 + v2; a3 += u3 + v3;
    }

    if (lane < 10) {
        float scale = 1.0f / (float)(d + 1);
        float4 bb = *reinterpret_cast<const float4*>(bias + cl * 4);
        float4 o;
        o.x = fmaf(scale, a0, bb.x);
        o.y = fmaf(scale, a1, bb.y);
        o.z = fmaf(scale, a2, bb.z);
        o.w = fmaf(scale, a3, bb.w);
        *reinterpret_cast<float4*>(out + (size_t)wid * NCLS + cl * 4) = o;
    }
}

extern "C" void kernel_launch(void* const* d_in, const int* in_sizes, int n_in,
                              void* d_out, int out_size, void* d_ws, size_t ws_size,
                              hipStream_t stream) {
    const float* x   = (const float*)d_in[0];
    const void*  adj = d_in[1];
    const float* W   = (const float*)d_in[2];
    const float* b   = (const float*)d_in[3];
    float* out = (float*)d_out;

    const int N = in_sizes[0] / NFEAT;   // 100000
    const int E = in_sizes[1] / 2;       // 3200000
    const int NB = (N + NCB - 1) / NCB;  // 391 coarse buckets
    const int GEMMB = (N + 63) / 64;     // 4 waves x 16 rows per block

    char* ws = (char*)d_ws;
    size_t off = 0;
    auto alloc = [&](size_t bytes) { char* p = ws + off; off += (bytes + 15) & ~size_t(15); return p; };

    unsigned short* xwb = (unsigned short*)alloc((size_t)N * NCLS * 2);   // 8 MB
    int*   cnt          = (int*)  alloc((size_t)N * sizeof(int));
    unsigned int* flag  = (unsigned int*)alloc(16);
    int*   ovf_cnt      = (int*)  alloc(16);
    unsigned short* Wb  = (unsigned short*)alloc((size_t)NPAD * NFEAT * 2);

    const size_t part_need = off
        + (((size_t)NB * P1B * SCAP * 4 + 15) & ~size_t(15))        // slices 51 MB
        + (((size_t)NB * P1B * 4 + 15) & ~size_t(15))               // slice_cnt 0.8 MB
        + (((size_t)N * 4 + 15) & ~size_t(15))                      // starts
        + (((size_t)NB * BCAP * 4 + 15) & ~size_t(15))              // src 25.6 MB
        + (size_t)OVF_CAP * 8;                                      // ovf ring
    const bool partition = (N <= NCB * 512) && (NB <= 512) && (E >= 512)
                           && (part_need <= ws_size);
    const size_t direct_need = off + (size_t)N * DM * sizeof(int);
    const bool direct = !partition && (direct_need <= ws_size);

    wconv_kernel<<<(NPAD * NFEAT + 255) / 256, 256, 0, stream>>>(W, Wb, flag, ovf_cnt);

    if (partition) {
        unsigned int* slices = (unsigned int*)alloc((size_t)NB * P1B * SCAP * 4);
        int* slice_cnt = (int*)alloc((size_t)NB * P1B * 4);
        int* starts = (int*)alloc((size_t)N * 4);
        int* src    = (int*)alloc((size_t)NB * BCAP * 4);
        unsigned long long* ovf = (unsigned long long*)alloc((size_t)OVF_CAP * 8);

        phase1_kernel<<<P1B, 256, 0, stream>>>(adj, slices, slice_cnt,
                                               ovf, ovf_cnt, E, N, NB);
        gemm_kernel<<<GEMMB, 256, 0, stream>>>(x, Wb, xwb, N);
        phase2_kernel<<<NB, 256, 0, stream>>>(slices, slice_cnt, ovf, ovf_cnt,
                                              starts, cnt, src, N);
        gather_kernel<<<(N * 64 + 255) / 256, 256, 0, stream>>>(
            xwb, starts, cnt, src, b, out, N, 0);
    } else if (direct) {
        int* src2 = (int*)alloc((size_t)N * DM * sizeof(int));
        hipMemsetAsync(cnt, 0, (size_t)N * sizeof(int), stream);
        detect_kernel<<<1, 512, 0, stream>>>((const unsigned int*)adj, flag);
        gemm_kernel<<<GEMMB, 256, 0, stream>>>(x, Wb, xwb, N);
        fused_bucket_kernel<<<(E + 255) / 256, 256, 0, stream>>>(adj, flag, cnt, src2, E, N);
        gather_kernel<<<(N * 64 + 255) / 256, 256, 0, stream>>>(
            xwb, nullptr, cnt, src2, b, out, N, DM);
    }
}